// Round 6
// baseline (370.218 us; speedup 1.0000x reference)
//
#include <hip/hip_runtime.h>
#include <cstdint>

#define N_NODES 50000
#define N_EDGES 1600000

#define NCOARSE 196                   // ceil(50000/256)
#define CBLK 256                      // blocks in coarse pass
#define ECHUNK (N_EDGES / CBLK)       // 6250 edges per block

#define OSL 4                         // outdeg slices
#define ONPS (N_NODES / OSL)          // 12500 nodes per slice
#define OPARTS 32
#define OCHUNK (N_EDGES / OPARTS)     // 50000

// ---- K1: per-block coarse histogram of dst>>8 (LDS atomics only) ----
__global__ void k_hist(const int* __restrict__ dst, unsigned* __restrict__ counts) {
    __shared__ unsigned hist[NCOARSE];
    for (int i = threadIdx.x; i < NCOARSE; i += 256) hist[i] = 0;
    __syncthreads();
    int base = blockIdx.x * ECHUNK;
    for (int i = threadIdx.x; i < ECHUNK; i += 256)
        atomicAdd(&hist[(unsigned)dst[base + i] >> 8], 1u);
    __syncthreads();
    for (int i = threadIdx.x; i < NCOARSE; i += 256)
        counts[blockIdx.x * NCOARSE + i] = hist[i];
}

// ---- K2: scan block-counts within each coarse bucket ----
__global__ void k_scanA(const unsigned* __restrict__ counts, unsigned* __restrict__ woff,
                        unsigned* __restrict__ tot) {
    __shared__ unsigned s[256];
    int c = blockIdx.x, t = threadIdx.x;
    unsigned v = counts[t * NCOARSE + c];
    s[t] = v; __syncthreads();
    for (int o = 1; o < 256; o <<= 1) {
        unsigned u = (t >= o) ? s[t - o] : 0u;
        __syncthreads(); s[t] += u; __syncthreads();
    }
    woff[t * NCOARSE + c] = s[t] - v;
    if (t == 255) tot[c] = s[255];
}

// ---- K3: scan bucket totals -> base[], plus row_ptr tail ----
__global__ void k_scanB(const unsigned* __restrict__ tot, unsigned* __restrict__ base,
                        unsigned* __restrict__ row_ptr) {
    __shared__ unsigned s[256];
    int t = threadIdx.x;
    unsigned v = (t < NCOARSE) ? tot[t] : 0u;
    s[t] = v; __syncthreads();
    for (int o = 1; o < 256; o <<= 1) {
        unsigned u = (t >= o) ? s[t - o] : 0u;
        __syncthreads(); s[t] += u; __syncthreads();
    }
    if (t < NCOARSE) base[t] = s[t] - v;
    if (t == NCOARSE - 1) base[NCOARSE] = s[t];   // == N_EDGES
    if (t == 0) row_ptr[N_NODES] = N_EDGES;
}

// ---- K4: coarse scatter into tmp arrays (LDS cursors, run-coalesced stores) ----
__global__ void k_scat1(const int* __restrict__ src, const int* __restrict__ dst,
                        const unsigned* __restrict__ base, const unsigned* __restrict__ woff,
                        int* __restrict__ tmp_s, int* __restrict__ tmp_d) {
    __shared__ unsigned cur[NCOARSE];
    int b = blockIdx.x, t = threadIdx.x;
    for (int i = t; i < NCOARSE; i += 256) cur[i] = base[i] + woff[b * NCOARSE + i];
    __syncthreads();
    int ebase = b * ECHUNK;
    for (int i = t; i < ECHUNK; i += 256) {
        int d = dst[ebase + i], sv = src[ebase + i];
        unsigned p = atomicAdd(&cur[(unsigned)d >> 8], 1u);
        tmp_d[p] = d; tmp_s[p] = sv;
    }
}

// ---- K5: fine scatter within each coarse bucket; emits row_ptr, inn, csr ----
__global__ void k_scat2(const int* __restrict__ tmp_s, const int* __restrict__ tmp_d,
                        const unsigned* __restrict__ base,
                        unsigned* __restrict__ row_ptr, float* __restrict__ inn,
                        int* __restrict__ csr) {
    __shared__ unsigned hist[256], cur[256], s[256];
    int c = blockIdx.x, t = threadIdx.x;
    unsigned beg = base[c], end = base[c + 1];
    hist[t] = 0;
    __syncthreads();
    for (unsigned i = beg + t; i < end; i += 256)
        atomicAdd(&hist[(unsigned)tmp_d[i] & 255u], 1u);
    __syncthreads();
    unsigned v = hist[t];
    s[t] = v; __syncthreads();
    for (int o = 1; o < 256; o <<= 1) {
        unsigned u = (t >= o) ? s[t - o] : 0u;
        __syncthreads(); s[t] += u; __syncthreads();
    }
    unsigned excl = s[t] - v;
    int node = c * 256 + t;
    if (node < N_NODES) {
        row_ptr[node] = beg + excl;
        inn[node] = rsqrtf((float)(v < 1u ? 1u : v));
    }
    cur[t] = beg + excl;
    __syncthreads();
    for (unsigned i = beg + t; i < end; i += 256) {
        int d = tmp_d[i], sv = tmp_s[i];
        unsigned p = atomicAdd(&cur[(unsigned)d & 255u], 1u);
        csr[p] = sv;
    }
}

// ---- K6: outdeg partial histograms (sliced LDS, non-atomic global stores) ----
__global__ void k_odp(const int* __restrict__ src, unsigned short* __restrict__ partial) {
    __shared__ unsigned h[ONPS];      // 48.8 KiB
    int slice = blockIdx.x & (OSL - 1), part = blockIdx.x >> 2;
    int lo = slice * ONPS;
    for (int i = threadIdx.x; i < ONPS; i += 256) h[i] = 0;
    __syncthreads();
    int ebase = part * OCHUNK;
    for (int i = threadIdx.x; i < OCHUNK; i += 256) {
        int sv = src[ebase + i] - lo;
        if ((unsigned)sv < (unsigned)ONPS) atomicAdd(&h[sv], 1u);
    }
    __syncthreads();
    unsigned short* out = partial + (size_t)(slice * OPARTS + part) * ONPS;
    for (int i = threadIdx.x; i < ONPS; i += 256) out[i] = (unsigned short)h[i];
}

// ---- K7: reduce outdeg partials -> on ----
__global__ void k_on(const unsigned short* __restrict__ partial, float* __restrict__ on) {
    int n = blockIdx.x * 256 + threadIdx.x;
    if (n >= N_NODES) return;
    int slice = n / ONPS, i = n % ONPS;
    const unsigned short* p = partial + (size_t)slice * OPARTS * ONPS + i;
    unsigned sum = 0;
    #pragma unroll
    for (int q = 0; q < OPARTS; ++q) sum += p[(size_t)q * ONPS];
    on[n] = rsqrtf((float)(sum < 1u ? 1u : sum));
}

// ---------------- GEMM helpers ----------------
#define FMA4(A, S, WV) { (A).x += (S)*(WV).x; (A).y += (S)*(WV).y; (A).z += (S)*(WV).z; (A).w += (S)*(WV).w; }

__device__ __forceinline__ unsigned bf16rn(float f) {
    unsigned u = __float_as_uint(f);
    return (u + 0x7fffu + ((u >> 16) & 1u)) >> 16;   // round-to-nearest-even bf16 bits
}

// GEMM1: h_bf16 = bf16((x * on[:,None]) @ W1)  (50000x128 @ 128x128), j-half per block
__global__ __launch_bounds__(256, 4) void gcn_gemm1_kernel(
        const float* __restrict__ x, const float* __restrict__ on,
        const float* __restrict__ W, unsigned* __restrict__ hb) {
    __shared__ float4 Ws[128 * 16];      // 32 KiB: half of W's columns
    int tid = threadIdx.x;
    int tile = blockIdx.x >> 1, half = blockIdx.x & 1;
    for (int i = tid; i < 128 * 16; i += 256) {
        int k = i >> 4, q = i & 15;
        Ws[i] = ((const float4*)W)[k * 32 + half * 16 + q];
    }
    __syncthreads();

    int jg = tid & 15;
    int ns = tid >> 4;
    int n0 = tile * 64 + ns * 4;

    float sc[4]; bool val[4];
    float4 acc[4];
    #pragma unroll
    for (int i = 0; i < 4; ++i) {
        int n = n0 + i; val[i] = (n < N_NODES);
        sc[i] = val[i] ? on[n] : 0.f;
        acc[i] = float4{0.f, 0.f, 0.f, 0.f};
    }

    const float4* xv4 = (const float4*)x;
    float4 xc[4], wc[4], xn[4], wn[4];
    #pragma unroll
    for (int i = 0; i < 4; ++i)
        xc[i] = val[i] ? xv4[(size_t)(n0 + i) * 32] : float4{0.f, 0.f, 0.f, 0.f};
    #pragma unroll
    for (int t = 0; t < 4; ++t) wc[t] = Ws[t * 16 + jg];

    for (int kc = 0; kc < 32; ++kc) {
        if (kc < 31) {
            #pragma unroll
            for (int i = 0; i < 4; ++i)
                xn[i] = val[i] ? xv4[(size_t)(n0 + i) * 32 + kc + 1] : float4{0.f, 0.f, 0.f, 0.f};
            #pragma unroll
            for (int t = 0; t < 4; ++t) wn[t] = Ws[(kc * 4 + 4 + t) * 16 + jg];
        }
        #pragma unroll
        for (int i = 0; i < 4; ++i) {
            FMA4(acc[i], xc[i].x, wc[0]);
            FMA4(acc[i], xc[i].y, wc[1]);
            FMA4(acc[i], xc[i].z, wc[2]);
            FMA4(acc[i], xc[i].w, wc[3]);
        }
        #pragma unroll
        for (int i = 0; i < 4; ++i) xc[i] = xn[i];
        #pragma unroll
        for (int t = 0; t < 4; ++t) wc[t] = wn[t];
    }
    #pragma unroll
    for (int i = 0; i < 4; ++i) {
        if (val[i]) {
            float ax = acc[i].x * sc[i], ay = acc[i].y * sc[i];
            float az = acc[i].z * sc[i], aw = acc[i].w * sc[i];
            uint2 p;
            p.x = bf16rn(ax) | (bf16rn(ay) << 16);
            p.y = bf16rn(az) | (bf16rn(aw) << 16);
            // features f0 = half*64 + jg*4 -> uint2 index = half*16 + jg in a 32-uint2 row
            ((uint2*)hb)[(size_t)(n0 + i) * 32 + half * 16 + jg] = p;
        }
    }
}

// GEMM2: h2 = (h1 * on[:,None]) @ W2  (50000x128 @ 128x64), fp32 out
__global__ __launch_bounds__(256, 4) void gcn_gemm2_kernel(
        const float* __restrict__ h1, const float* __restrict__ on,
        const float* __restrict__ W, float* __restrict__ h2) {
    __shared__ float4 Ws[128 * 16];      // 32 KiB: all of W2
    int tid = threadIdx.x;
    int tile = blockIdx.x;
    for (int i = tid; i < 128 * 16; i += 256) Ws[i] = ((const float4*)W)[i];
    __syncthreads();

    int jg = tid & 15;
    int ns = tid >> 4;
    int n0 = tile * 64 + ns * 4;

    float sc[4]; bool val[4];
    float4 acc[4];
    #pragma unroll
    for (int i = 0; i < 4; ++i) {
        int n = n0 + i; val[i] = (n < N_NODES);
        sc[i] = val[i] ? on[n] : 0.f;
        acc[i] = float4{0.f, 0.f, 0.f, 0.f};
    }

    const float4* xv4 = (const float4*)h1;
    float4 xc[4], wc[4], xn[4], wn[4];
    #pragma unroll
    for (int i = 0; i < 4; ++i)
        xc[i] = val[i] ? xv4[(size_t)(n0 + i) * 32] : float4{0.f, 0.f, 0.f, 0.f};
    #pragma unroll
    for (int t = 0; t < 4; ++t) wc[t] = Ws[t * 16 + jg];

    for (int kc = 0; kc < 32; ++kc) {
        if (kc < 31) {
            #pragma unroll
            for (int i = 0; i < 4; ++i)
                xn[i] = val[i] ? xv4[(size_t)(n0 + i) * 32 + kc + 1] : float4{0.f, 0.f, 0.f, 0.f};
            #pragma unroll
            for (int t = 0; t < 4; ++t) wn[t] = Ws[(kc * 4 + 4 + t) * 16 + jg];
        }
        #pragma unroll
        for (int i = 0; i < 4; ++i) {
            FMA4(acc[i], xc[i].x, wc[0]);
            FMA4(acc[i], xc[i].y, wc[1]);
            FMA4(acc[i], xc[i].z, wc[2]);
            FMA4(acc[i], xc[i].w, wc[3]);
        }
        #pragma unroll
        for (int i = 0; i < 4; ++i) xc[i] = xn[i];
        #pragma unroll
        for (int t = 0; t < 4; ++t) wc[t] = wn[t];
    }
    #pragma unroll
    for (int i = 0; i < 4; ++i) {
        if (val[i]) {
            acc[i].x *= sc[i]; acc[i].y *= sc[i]; acc[i].z *= sc[i]; acc[i].w *= sc[i];
            ((float4*)h2)[(size_t)(n0 + i) * 16 + jg] = acc[i];
        }
    }
}

// ---- agg1: h1 = relu(segsum(h_bf16[src]) * inn + b1); wave-per-node, shfl edge bcast ----
__global__ __launch_bounds__(256) void gcn_agg1_kernel(
        const unsigned* __restrict__ hb, const int* __restrict__ csr,
        const unsigned int* __restrict__ row_ptr,
        const float* __restrict__ inn, const float* __restrict__ b1,
        float* __restrict__ h1) {
    int lane = threadIdx.x & 63;
    int n = blockIdx.x * 4 + (threadIdx.x >> 6);   // wave-per-node; 12500 blocks exactly
    unsigned beg = row_ptr[n], end = row_ptr[n + 1];
    float ax = 0.f, ay = 0.f;
    for (unsigned base = beg; base < end; base += 64) {
        unsigned e = base + lane;
        int r = (e < end) ? csr[e] : 0;
        int m = (int)(end - base); if (m > 64) m = 64;
        for (int j = 0; j < m; ++j) {
            unsigned idx = (unsigned)__shfl(r, j);
            unsigned v = hb[idx * 64u + (unsigned)lane];
            ax += __uint_as_float(v << 16);
            ay += __uint_as_float(v & 0xffff0000u);
        }
    }
    float sc = inn[n];
    float2 b = ((const float2*)b1)[lane];
    float2 o;
    o.x = fmaxf(ax * sc + b.x, 0.f);
    o.y = fmaxf(ay * sc + b.y, 0.f);
    ((float2*)h1)[(size_t)n * 64 + lane] = o;
}

// ---- agg2: out = segsum(h2[src]) * inn + b2; wave-per-node fp32 ----
__global__ __launch_bounds__(256) void gcn_agg2_kernel(
        const float* __restrict__ h2, const int* __restrict__ csr,
        const unsigned int* __restrict__ row_ptr,
        const float* __restrict__ inn, const float* __restrict__ b2,
        float* __restrict__ out) {
    int lane = threadIdx.x & 63;
    int n = blockIdx.x * 4 + (threadIdx.x >> 6);
    unsigned beg = row_ptr[n], end = row_ptr[n + 1];
    float acc = 0.f;
    for (unsigned base = beg; base < end; base += 64) {
        unsigned e = base + lane;
        int r = (e < end) ? csr[e] : 0;
        int m = (int)(end - base); if (m > 64) m = 64;
        for (int j = 0; j < m; ++j) {
            unsigned idx = (unsigned)__shfl(r, j);
            acc += h2[idx * 64u + (unsigned)lane];
        }
    }
    out[(size_t)n * 64 + lane] = acc * inn[n] + b2[lane];
}

extern "C" void kernel_launch(void* const* d_in, const int* in_sizes, int n_in,
                              void* d_out, int out_size, void* d_ws, size_t ws_size,
                              hipStream_t stream) {
    const float* x  = (const float*)d_in[0];
    const float* W1 = (const float*)d_in[1];
    const float* b1 = (const float*)d_in[2];
    const float* W2 = (const float*)d_in[3];
    const float* b2 = (const float*)d_in[4];
    const int*   src = (const int*)d_in[5];
    const int*   dst = (const int*)d_in[6];
    float* out = (float*)d_out;

    char* ws = (char*)d_ws;
    size_t off = 0;
    auto alloc = [&](size_t bytes) -> void* {
        void* p = ws + off;
        off += (bytes + 255) & ~(size_t)255;
        return p;
    };

    float*        on      = (float*)alloc((size_t)N_NODES * 4);
    float*        inn     = (float*)alloc((size_t)N_NODES * 4);
    unsigned int* row_ptr = (unsigned int*)alloc((size_t)(N_NODES + 1) * 4);
    unsigned int* base    = (unsigned int*)alloc((NCOARSE + 1) * 4);
    unsigned int* tot     = (unsigned int*)alloc(NCOARSE * 4);
    int*          csr     = (int*)alloc((size_t)N_EDGES * 4);
    float*        h       = (float*)alloc((size_t)N_NODES * 128 * 4);   // tmp_s/tmp_d, h_bf16, later h2
    float*        h1      = (float*)alloc((size_t)N_NODES * 128 * 4);   // partial/counts/woff, later h1

    // aliases into dead regions
    int*            tmp_d   = (int*)h;                                   // 6.4 MB
    int*            tmp_s   = (int*)((char*)h + (size_t)N_EDGES * 4);    // 6.4 MB
    unsigned short* partial = (unsigned short*)h1;                       // 3.2 MB
    unsigned int*   counts  = (unsigned int*)((char*)h1 + (4u << 20));   // 200 KB
    unsigned int*   woff    = (unsigned int*)((char*)h1 + (8u << 20));   // 200 KB
    unsigned*       hb      = (unsigned*)h;  // 12.8 MB bf16 table (tmp_* dead by gemm1)
    float*          h2      = h;             // hb dead after agg1

    // ---- CSR build via 2-level counting sort (zero global atomics) ----
    k_hist <<<CBLK, 256, 0, stream>>>(dst, counts);
    k_scanA<<<NCOARSE, 256, 0, stream>>>(counts, woff, tot);
    k_scanB<<<1, 256, 0, stream>>>(tot, base, row_ptr);
    k_scat1<<<CBLK, 256, 0, stream>>>(src, dst, base, woff, tmp_s, tmp_d);
    k_scat2<<<NCOARSE, 256, 0, stream>>>(tmp_s, tmp_d, base, row_ptr, inn, csr);

    // ---- outdeg -> on (sliced LDS histograms) ----
    k_odp<<<OSL * OPARTS, 256, 0, stream>>>(src, partial);
    k_on <<<(N_NODES + 255) / 256, 256, 0, stream>>>(partial, on);

    // ---- GCN layers ----
    int ntiles = (N_NODES + 63) / 64;         // 782
    gcn_gemm1_kernel<<<ntiles * 2, 256, 0, stream>>>(x, on, W1, hb);
    gcn_agg1_kernel<<<N_NODES / 4, 256, 0, stream>>>(hb, csr, row_ptr, inn, b1, h1);
    gcn_gemm2_kernel<<<ntiles, 256, 0, stream>>>(h1, on, W2, h2);
    gcn_agg2_kernel<<<N_NODES / 4, 256, 0, stream>>>(h2, csr, row_ptr, inn, b2, out);
}

// Round 7
// 278.121 us; speedup vs baseline: 1.3311x; 1.3311x over previous
//
#include <hip/hip_runtime.h>
#include <cstdint>

#define N_NODES 50000
#define N_EDGES 1600000

#define NCOARSE 196                   // ceil(50000/256)
#define CBLK 256                      // blocks in coarse pass
#define ECHUNK (N_EDGES / CBLK)       // 6250 edges per block

#define OSL 4                         // outdeg slices
#define ONPS (N_NODES / OSL)          // 12500 nodes per slice
#define OPARTS 32
#define OCHUNK (N_EDGES / OPARTS)     // 50000

// ---- K1: per-block coarse histogram of dst>>8 (LDS atomics only) ----
__global__ void k_hist(const int* __restrict__ dst, unsigned* __restrict__ counts) {
    __shared__ unsigned hist[NCOARSE];
    for (int i = threadIdx.x; i < NCOARSE; i += 256) hist[i] = 0;
    __syncthreads();
    int base = blockIdx.x * ECHUNK;
    for (int i = threadIdx.x; i < ECHUNK; i += 256)
        atomicAdd(&hist[(unsigned)dst[base + i] >> 8], 1u);
    __syncthreads();
    for (int i = threadIdx.x; i < NCOARSE; i += 256)
        counts[blockIdx.x * NCOARSE + i] = hist[i];
}

// ---- K2: scan block-counts within each coarse bucket ----
__global__ void k_scanA(const unsigned* __restrict__ counts, unsigned* __restrict__ woff,
                        unsigned* __restrict__ tot) {
    __shared__ unsigned s[256];
    int c = blockIdx.x, t = threadIdx.x;
    unsigned v = counts[t * NCOARSE + c];
    s[t] = v; __syncthreads();
    for (int o = 1; o < 256; o <<= 1) {
        unsigned u = (t >= o) ? s[t - o] : 0u;
        __syncthreads(); s[t] += u; __syncthreads();
    }
    woff[t * NCOARSE + c] = s[t] - v;
    if (t == 255) tot[c] = s[255];
}

// ---- K3: scan bucket totals -> base[], plus row_ptr tail ----
__global__ void k_scanB(const unsigned* __restrict__ tot, unsigned* __restrict__ base,
                        unsigned* __restrict__ row_ptr) {
    __shared__ unsigned s[256];
    int t = threadIdx.x;
    unsigned v = (t < NCOARSE) ? tot[t] : 0u;
    s[t] = v; __syncthreads();
    for (int o = 1; o < 256; o <<= 1) {
        unsigned u = (t >= o) ? s[t - o] : 0u;
        __syncthreads(); s[t] += u; __syncthreads();
    }
    if (t < NCOARSE) base[t] = s[t] - v;
    if (t == NCOARSE - 1) base[NCOARSE] = s[t];   // == N_EDGES
    if (t == 0) row_ptr[N_NODES] = N_EDGES;
}

// ---- K4: coarse scatter into tmp arrays (LDS cursors, run-coalesced stores) ----
__global__ void k_scat1(const int* __restrict__ src, const int* __restrict__ dst,
                        const unsigned* __restrict__ base, const unsigned* __restrict__ woff,
                        int* __restrict__ tmp_s, int* __restrict__ tmp_d) {
    __shared__ unsigned cur[NCOARSE];
    int b = blockIdx.x, t = threadIdx.x;
    for (int i = t; i < NCOARSE; i += 256) cur[i] = base[i] + woff[b * NCOARSE + i];
    __syncthreads();
    int ebase = b * ECHUNK;
    for (int i = t; i < ECHUNK; i += 256) {
        int d = dst[ebase + i], sv = src[ebase + i];
        unsigned p = atomicAdd(&cur[(unsigned)d >> 8], 1u);
        tmp_d[p] = d; tmp_s[p] = sv;
    }
}

// ---- K5: fine scatter within each coarse bucket; emits row_ptr, inn, csr ----
__global__ void k_scat2(const int* __restrict__ tmp_s, const int* __restrict__ tmp_d,
                        const unsigned* __restrict__ base,
                        unsigned* __restrict__ row_ptr, float* __restrict__ inn,
                        int* __restrict__ csr) {
    __shared__ unsigned hist[256], cur[256], s[256];
    int c = blockIdx.x, t = threadIdx.x;
    unsigned beg = base[c], end = base[c + 1];
    hist[t] = 0;
    __syncthreads();
    for (unsigned i = beg + t; i < end; i += 256)
        atomicAdd(&hist[(unsigned)tmp_d[i] & 255u], 1u);
    __syncthreads();
    unsigned v = hist[t];
    s[t] = v; __syncthreads();
    for (int o = 1; o < 256; o <<= 1) {
        unsigned u = (t >= o) ? s[t - o] : 0u;
        __syncthreads(); s[t] += u; __syncthreads();
    }
    unsigned excl = s[t] - v;
    int node = c * 256 + t;
    if (node < N_NODES) {
        row_ptr[node] = beg + excl;
        inn[node] = rsqrtf((float)(v < 1u ? 1u : v));
    }
    cur[t] = beg + excl;
    __syncthreads();
    for (unsigned i = beg + t; i < end; i += 256) {
        int d = tmp_d[i], sv = tmp_s[i];
        unsigned p = atomicAdd(&cur[(unsigned)d & 255u], 1u);
        csr[p] = sv;
    }
}

// ---- K6: outdeg partial histograms (sliced LDS, non-atomic global stores) ----
__global__ void k_odp(const int* __restrict__ src, unsigned short* __restrict__ partial) {
    __shared__ unsigned h[ONPS];      // 48.8 KiB
    int slice = blockIdx.x & (OSL - 1), part = blockIdx.x >> 2;
    int lo = slice * ONPS;
    for (int i = threadIdx.x; i < ONPS; i += 256) h[i] = 0;
    __syncthreads();
    int ebase = part * OCHUNK;
    for (int i = threadIdx.x; i < OCHUNK; i += 256) {
        int sv = src[ebase + i] - lo;
        if ((unsigned)sv < (unsigned)ONPS) atomicAdd(&h[sv], 1u);
    }
    __syncthreads();
    unsigned short* out = partial + (size_t)(slice * OPARTS + part) * ONPS;
    for (int i = threadIdx.x; i < ONPS; i += 256) out[i] = (unsigned short)h[i];
}

// ---- K7: reduce outdeg partials -> on ----
__global__ void k_on(const unsigned short* __restrict__ partial, float* __restrict__ on) {
    int n = blockIdx.x * 256 + threadIdx.x;
    if (n >= N_NODES) return;
    int slice = n / ONPS, i = n % ONPS;
    const unsigned short* p = partial + (size_t)slice * OPARTS * ONPS + i;
    unsigned sum = 0;
    #pragma unroll
    for (int q = 0; q < OPARTS; ++q) sum += p[(size_t)q * ONPS];
    on[n] = rsqrtf((float)(sum < 1u ? 1u : sum));
}

// ---------------- GEMM helpers ----------------
#define FMA4(A, S, WV) { (A).x += (S)*(WV).x; (A).y += (S)*(WV).y; (A).z += (S)*(WV).z; (A).w += (S)*(WV).w; }

__device__ __forceinline__ unsigned bf16rn(float f) {
    unsigned u = __float_as_uint(f);
    return (u + 0x7fffu + ((u >> 16) & 1u)) >> 16;   // round-to-nearest-even bf16 bits
}

// GEMM1: h_bf16 = bf16((x * on[:,None]) @ W1)  (50000x128 @ 128x128), j-half per block
__global__ __launch_bounds__(256, 4) void gcn_gemm1_kernel(
        const float* __restrict__ x, const float* __restrict__ on,
        const float* __restrict__ W, unsigned* __restrict__ hb) {
    __shared__ float4 Ws[128 * 16];      // 32 KiB: half of W's columns
    int tid = threadIdx.x;
    int tile = blockIdx.x >> 1, half = blockIdx.x & 1;
    for (int i = tid; i < 128 * 16; i += 256) {
        int k = i >> 4, q = i & 15;
        Ws[i] = ((const float4*)W)[k * 32 + half * 16 + q];
    }
    __syncthreads();

    int jg = tid & 15;
    int ns = tid >> 4;
    int n0 = tile * 64 + ns * 4;

    float sc[4]; bool val[4];
    float4 acc[4];
    #pragma unroll
    for (int i = 0; i < 4; ++i) {
        int n = n0 + i; val[i] = (n < N_NODES);
        sc[i] = val[i] ? on[n] : 0.f;
        acc[i] = float4{0.f, 0.f, 0.f, 0.f};
    }

    const float4* xv4 = (const float4*)x;
    float4 xc[4], wc[4], xn[4], wn[4];
    #pragma unroll
    for (int i = 0; i < 4; ++i)
        xc[i] = val[i] ? xv4[(size_t)(n0 + i) * 32] : float4{0.f, 0.f, 0.f, 0.f};
    #pragma unroll
    for (int t = 0; t < 4; ++t) wc[t] = Ws[t * 16 + jg];

    for (int kc = 0; kc < 32; ++kc) {
        if (kc < 31) {
            #pragma unroll
            for (int i = 0; i < 4; ++i)
                xn[i] = val[i] ? xv4[(size_t)(n0 + i) * 32 + kc + 1] : float4{0.f, 0.f, 0.f, 0.f};
            #pragma unroll
            for (int t = 0; t < 4; ++t) wn[t] = Ws[(kc * 4 + 4 + t) * 16 + jg];
        }
        #pragma unroll
        for (int i = 0; i < 4; ++i) {
            FMA4(acc[i], xc[i].x, wc[0]);
            FMA4(acc[i], xc[i].y, wc[1]);
            FMA4(acc[i], xc[i].z, wc[2]);
            FMA4(acc[i], xc[i].w, wc[3]);
        }
        #pragma unroll
        for (int i = 0; i < 4; ++i) xc[i] = xn[i];
        #pragma unroll
        for (int t = 0; t < 4; ++t) wc[t] = wn[t];
    }
    #pragma unroll
    for (int i = 0; i < 4; ++i) {
        if (val[i]) {
            float ax = acc[i].x * sc[i], ay = acc[i].y * sc[i];
            float az = acc[i].z * sc[i], aw = acc[i].w * sc[i];
            uint2 p;
            p.x = bf16rn(ax) | (bf16rn(ay) << 16);
            p.y = bf16rn(az) | (bf16rn(aw) << 16);
            ((uint2*)hb)[(size_t)(n0 + i) * 32 + half * 16 + jg] = p;
        }
    }
}

// GEMM2: h2 = (h1 * on[:,None]) @ W2  (50000x128 @ 128x64), fp32 out
__global__ __launch_bounds__(256, 4) void gcn_gemm2_kernel(
        const float* __restrict__ h1, const float* __restrict__ on,
        const float* __restrict__ W, float* __restrict__ h2) {
    __shared__ float4 Ws[128 * 16];      // 32 KiB: all of W2
    int tid = threadIdx.x;
    int tile = blockIdx.x;
    for (int i = tid; i < 128 * 16; i += 256) Ws[i] = ((const float4*)W)[i];
    __syncthreads();

    int jg = tid & 15;
    int ns = tid >> 4;
    int n0 = tile * 64 + ns * 4;

    float sc[4]; bool val[4];
    float4 acc[4];
    #pragma unroll
    for (int i = 0; i < 4; ++i) {
        int n = n0 + i; val[i] = (n < N_NODES);
        sc[i] = val[i] ? on[n] : 0.f;
        acc[i] = float4{0.f, 0.f, 0.f, 0.f};
    }

    const float4* xv4 = (const float4*)h1;
    float4 xc[4], wc[4], xn[4], wn[4];
    #pragma unroll
    for (int i = 0; i < 4; ++i)
        xc[i] = val[i] ? xv4[(size_t)(n0 + i) * 32] : float4{0.f, 0.f, 0.f, 0.f};
    #pragma unroll
    for (int t = 0; t < 4; ++t) wc[t] = Ws[t * 16 + jg];

    for (int kc = 0; kc < 32; ++kc) {
        if (kc < 31) {
            #pragma unroll
            for (int i = 0; i < 4; ++i)
                xn[i] = val[i] ? xv4[(size_t)(n0 + i) * 32 + kc + 1] : float4{0.f, 0.f, 0.f, 0.f};
            #pragma unroll
            for (int t = 0; t < 4; ++t) wn[t] = Ws[(kc * 4 + 4 + t) * 16 + jg];
        }
        #pragma unroll
        for (int i = 0; i < 4; ++i) {
            FMA4(acc[i], xc[i].x, wc[0]);
            FMA4(acc[i], xc[i].y, wc[1]);
            FMA4(acc[i], xc[i].z, wc[2]);
            FMA4(acc[i], xc[i].w, wc[3]);
        }
        #pragma unroll
        for (int i = 0; i < 4; ++i) xc[i] = xn[i];
        #pragma unroll
        for (int t = 0; t < 4; ++t) wc[t] = wn[t];
    }
    #pragma unroll
    for (int i = 0; i < 4; ++i) {
        if (val[i]) {
            acc[i].x *= sc[i]; acc[i].y *= sc[i]; acc[i].z *= sc[i]; acc[i].w *= sc[i];
            ((float4*)h2)[(size_t)(n0 + i) * 16 + jg] = acc[i];
        }
    }
}

// ---- agg1: h1 = relu(segsum(h_bf16[src]) * inn + b1); wave-per-node, 8-deep MLP ----
__global__ __launch_bounds__(256) void gcn_agg1_kernel(
        const unsigned* __restrict__ hb, const int* __restrict__ csr,
        const unsigned int* __restrict__ row_ptr,
        const float* __restrict__ inn, const float* __restrict__ b1,
        float* __restrict__ h1) {
    int lane = threadIdx.x & 63;
    int n = blockIdx.x * 4 + (threadIdx.x >> 6);   // wave-per-node; 12500 blocks exactly
    unsigned beg = row_ptr[n], end = row_ptr[n + 1];
    float ax = 0.f, ay = 0.f;
    for (unsigned base = beg; base < end; base += 64) {
        unsigned e = base + lane;
        int r = (e < end) ? csr[e] : 0;
        int m = (int)(end - base); if (m > 64) m = 64;
        int j = 0;
        for (; j + 8 <= m; j += 8) {
            unsigned v0 = hb[(unsigned)__builtin_amdgcn_readlane(r, j    ) * 64u + (unsigned)lane];
            unsigned v1 = hb[(unsigned)__builtin_amdgcn_readlane(r, j + 1) * 64u + (unsigned)lane];
            unsigned v2 = hb[(unsigned)__builtin_amdgcn_readlane(r, j + 2) * 64u + (unsigned)lane];
            unsigned v3 = hb[(unsigned)__builtin_amdgcn_readlane(r, j + 3) * 64u + (unsigned)lane];
            unsigned v4 = hb[(unsigned)__builtin_amdgcn_readlane(r, j + 4) * 64u + (unsigned)lane];
            unsigned v5 = hb[(unsigned)__builtin_amdgcn_readlane(r, j + 5) * 64u + (unsigned)lane];
            unsigned v6 = hb[(unsigned)__builtin_amdgcn_readlane(r, j + 6) * 64u + (unsigned)lane];
            unsigned v7 = hb[(unsigned)__builtin_amdgcn_readlane(r, j + 7) * 64u + (unsigned)lane];
            ax += __uint_as_float(v0 << 16); ay += __uint_as_float(v0 & 0xffff0000u);
            ax += __uint_as_float(v1 << 16); ay += __uint_as_float(v1 & 0xffff0000u);
            ax += __uint_as_float(v2 << 16); ay += __uint_as_float(v2 & 0xffff0000u);
            ax += __uint_as_float(v3 << 16); ay += __uint_as_float(v3 & 0xffff0000u);
            ax += __uint_as_float(v4 << 16); ay += __uint_as_float(v4 & 0xffff0000u);
            ax += __uint_as_float(v5 << 16); ay += __uint_as_float(v5 & 0xffff0000u);
            ax += __uint_as_float(v6 << 16); ay += __uint_as_float(v6 & 0xffff0000u);
            ax += __uint_as_float(v7 << 16); ay += __uint_as_float(v7 & 0xffff0000u);
        }
        for (; j < m; ++j) {
            unsigned v = hb[(unsigned)__builtin_amdgcn_readlane(r, j) * 64u + (unsigned)lane];
            ax += __uint_as_float(v << 16); ay += __uint_as_float(v & 0xffff0000u);
        }
    }
    float sc = inn[n];
    float2 b = ((const float2*)b1)[lane];
    float2 o;
    o.x = fmaxf(ax * sc + b.x, 0.f);
    o.y = fmaxf(ay * sc + b.y, 0.f);
    ((float2*)h1)[(size_t)n * 64 + lane] = o;
}

// ---- agg2: out = segsum(h2[src]) * inn + b2; wave-per-node fp32, 8-deep MLP ----
__global__ __launch_bounds__(256) void gcn_agg2_kernel(
        const float* __restrict__ h2, const int* __restrict__ csr,
        const unsigned int* __restrict__ row_ptr,
        const float* __restrict__ inn, const float* __restrict__ b2,
        float* __restrict__ out) {
    int lane = threadIdx.x & 63;
    int n = blockIdx.x * 4 + (threadIdx.x >> 6);
    unsigned beg = row_ptr[n], end = row_ptr[n + 1];
    float acc = 0.f;
    for (unsigned base = beg; base < end; base += 64) {
        unsigned e = base + lane;
        int r = (e < end) ? csr[e] : 0;
        int m = (int)(end - base); if (m > 64) m = 64;
        int j = 0;
        for (; j + 8 <= m; j += 8) {
            float v0 = h2[(unsigned)__builtin_amdgcn_readlane(r, j    ) * 64u + (unsigned)lane];
            float v1 = h2[(unsigned)__builtin_amdgcn_readlane(r, j + 1) * 64u + (unsigned)lane];
            float v2 = h2[(unsigned)__builtin_amdgcn_readlane(r, j + 2) * 64u + (unsigned)lane];
            float v3 = h2[(unsigned)__builtin_amdgcn_readlane(r, j + 3) * 64u + (unsigned)lane];
            float v4 = h2[(unsigned)__builtin_amdgcn_readlane(r, j + 4) * 64u + (unsigned)lane];
            float v5 = h2[(unsigned)__builtin_amdgcn_readlane(r, j + 5) * 64u + (unsigned)lane];
            float v6 = h2[(unsigned)__builtin_amdgcn_readlane(r, j + 6) * 64u + (unsigned)lane];
            float v7 = h2[(unsigned)__builtin_amdgcn_readlane(r, j + 7) * 64u + (unsigned)lane];
            acc += v0 + v1 + v2 + v3 + v4 + v5 + v6 + v7;
        }
        for (; j < m; ++j)
            acc += h2[(unsigned)__builtin_amdgcn_readlane(r, j) * 64u + (unsigned)lane];
    }
    out[(size_t)n * 64 + lane] = acc * inn[n] + b2[lane];
}

extern "C" void kernel_launch(void* const* d_in, const int* in_sizes, int n_in,
                              void* d_out, int out_size, void* d_ws, size_t ws_size,
                              hipStream_t stream) {
    const float* x  = (const float*)d_in[0];
    const float* W1 = (const float*)d_in[1];
    const float* b1 = (const float*)d_in[2];
    const float* W2 = (const float*)d_in[3];
    const float* b2 = (const float*)d_in[4];
    const int*   src = (const int*)d_in[5];
    const int*   dst = (const int*)d_in[6];
    float* out = (float*)d_out;

    char* ws = (char*)d_ws;
    size_t off = 0;
    auto alloc = [&](size_t bytes) -> void* {
        void* p = ws + off;
        off += (bytes + 255) & ~(size_t)255;
        return p;
    };

    float*        on      = (float*)alloc((size_t)N_NODES * 4);
    float*        inn     = (float*)alloc((size_t)N_NODES * 4);
    unsigned int* row_ptr = (unsigned int*)alloc((size_t)(N_NODES + 1) * 4);
    unsigned int* base    = (unsigned int*)alloc((NCOARSE + 1) * 4);
    unsigned int* tot     = (unsigned int*)alloc(NCOARSE * 4);
    int*          csr     = (int*)alloc((size_t)N_EDGES * 4);
    float*        h       = (float*)alloc((size_t)N_NODES * 128 * 4);   // tmp_s/tmp_d, h_bf16, later h2
    float*        h1      = (float*)alloc((size_t)N_NODES * 128 * 4);   // partial/counts/woff, later h1

    // aliases into dead regions
    int*            tmp_d   = (int*)h;                                   // 6.4 MB
    int*            tmp_s   = (int*)((char*)h + (size_t)N_EDGES * 4);    // 6.4 MB
    unsigned short* partial = (unsigned short*)h1;                       // 3.2 MB
    unsigned int*   counts  = (unsigned int*)((char*)h1 + (4u << 20));   // 200 KB
    unsigned int*   woff    = (unsigned int*)((char*)h1 + (8u << 20));   // 200 KB
    unsigned*       hb      = (unsigned*)h;  // 12.8 MB bf16 table (tmp_* dead by gemm1)
    float*          h2      = h;             // hb dead after agg1

    // ---- CSR build via 2-level counting sort (zero global atomics) ----
    k_hist <<<CBLK, 256, 0, stream>>>(dst, counts);
    k_scanA<<<NCOARSE, 256, 0, stream>>>(counts, woff, tot);
    k_scanB<<<1, 256, 0, stream>>>(tot, base, row_ptr);
    k_scat1<<<CBLK, 256, 0, stream>>>(src, dst, base, woff, tmp_s, tmp_d);
    k_scat2<<<NCOARSE, 256, 0, stream>>>(tmp_s, tmp_d, base, row_ptr, inn, csr);

    // ---- outdeg -> on (sliced LDS histograms) ----
    k_odp<<<OSL * OPARTS, 256, 0, stream>>>(src, partial);
    k_on <<<(N_NODES + 255) / 256, 256, 0, stream>>>(partial, on);

    // ---- GCN layers ----
    int ntiles = (N_NODES + 63) / 64;         // 782
    gcn_gemm1_kernel<<<ntiles * 2, 256, 0, stream>>>(x, on, W1, hb);
    gcn_agg1_kernel<<<N_NODES / 4, 256, 0, stream>>>(hb, csr, row_ptr, inn, b1, h1);
    gcn_gemm2_kernel<<<ntiles, 256, 0, stream>>>(h1, on, W2, h2);
    gcn_agg2_kernel<<<N_NODES / 4, 256, 0, stream>>>(h2, csr, row_ptr, inn, b2, out);
}

// Round 8
// 231.195 us; speedup vs baseline: 1.6013x; 1.2030x over previous
//
#include <hip/hip_runtime.h>
#include <cstdint>

#define N_NODES 50000
#define N_EDGES 1600000

#define NCOARSE 196                   // ceil(50000/256)
#define CBLK 256                      // blocks in coarse pass
#define ECHUNK (N_EDGES / CBLK)       // 6250 edges per block

#define OSL2 2                        // outdeg slices
#define ONPS2 (N_NODES / OSL2)        // 25000 nodes per slice
#define ONW (ONPS2 / 2)               // 12500 packed u32 words per slice
#define OPARTS2 256
#define OCH2 (N_EDGES / OPARTS2)      // 6250 edges per part

// ---- K1: per-block coarse histogram of dst>>8 (LDS atomics only) ----
__global__ void k_hist(const int* __restrict__ dst, unsigned* __restrict__ counts) {
    __shared__ unsigned hist[NCOARSE];
    for (int i = threadIdx.x; i < NCOARSE; i += 256) hist[i] = 0;
    __syncthreads();
    int base = blockIdx.x * ECHUNK;
    for (int i = threadIdx.x; i < ECHUNK; i += 256)
        atomicAdd(&hist[(unsigned)dst[base + i] >> 8], 1u);
    __syncthreads();
    for (int i = threadIdx.x; i < NCOARSE; i += 256)
        counts[blockIdx.x * NCOARSE + i] = hist[i];
}

// ---- K2: scan block-counts within each coarse bucket ----
__global__ void k_scanA(const unsigned* __restrict__ counts, unsigned* __restrict__ woff,
                        unsigned* __restrict__ tot) {
    __shared__ unsigned s[256];
    int c = blockIdx.x, t = threadIdx.x;
    unsigned v = counts[t * NCOARSE + c];
    s[t] = v; __syncthreads();
    for (int o = 1; o < 256; o <<= 1) {
        unsigned u = (t >= o) ? s[t - o] : 0u;
        __syncthreads(); s[t] += u; __syncthreads();
    }
    woff[t * NCOARSE + c] = s[t] - v;
    if (t == 255) tot[c] = s[255];
}

// ---- K3: scan bucket totals -> base[], plus row_ptr tail ----
__global__ void k_scanB(const unsigned* __restrict__ tot, unsigned* __restrict__ base,
                        unsigned* __restrict__ row_ptr) {
    __shared__ unsigned s[256];
    int t = threadIdx.x;
    unsigned v = (t < NCOARSE) ? tot[t] : 0u;
    s[t] = v; __syncthreads();
    for (int o = 1; o < 256; o <<= 1) {
        unsigned u = (t >= o) ? s[t - o] : 0u;
        __syncthreads(); s[t] += u; __syncthreads();
    }
    if (t < NCOARSE) base[t] = s[t] - v;
    if (t == NCOARSE - 1) base[NCOARSE] = s[t];   // == N_EDGES
    if (t == 0) row_ptr[N_NODES] = N_EDGES;
}

// ---- K4: coarse scatter into tmp arrays (LDS cursors, run-coalesced stores) ----
__global__ void k_scat1(const int* __restrict__ src, const int* __restrict__ dst,
                        const unsigned* __restrict__ base, const unsigned* __restrict__ woff,
                        int* __restrict__ tmp_s, int* __restrict__ tmp_d) {
    __shared__ unsigned cur[NCOARSE];
    int b = blockIdx.x, t = threadIdx.x;
    for (int i = t; i < NCOARSE; i += 256) cur[i] = base[i] + woff[b * NCOARSE + i];
    __syncthreads();
    int ebase = b * ECHUNK;
    for (int i = t; i < ECHUNK; i += 256) {
        int d = dst[ebase + i], sv = src[ebase + i];
        unsigned p = atomicAdd(&cur[(unsigned)d >> 8], 1u);
        tmp_d[p] = d; tmp_s[p] = sv;
    }
}

// ---- K5: fine scatter within each coarse bucket; emits row_ptr, inn, csr ----
__global__ void k_scat2(const int* __restrict__ tmp_s, const int* __restrict__ tmp_d,
                        const unsigned* __restrict__ base,
                        unsigned* __restrict__ row_ptr, float* __restrict__ inn,
                        int* __restrict__ csr) {
    __shared__ unsigned hist[256], cur[256], s[256];
    int c = blockIdx.x, t = threadIdx.x;
    unsigned beg = base[c], end = base[c + 1];
    hist[t] = 0;
    __syncthreads();
    for (unsigned i = beg + t; i < end; i += 256)
        atomicAdd(&hist[(unsigned)tmp_d[i] & 255u], 1u);
    __syncthreads();
    unsigned v = hist[t];
    s[t] = v; __syncthreads();
    for (int o = 1; o < 256; o <<= 1) {
        unsigned u = (t >= o) ? s[t - o] : 0u;
        __syncthreads(); s[t] += u; __syncthreads();
    }
    unsigned excl = s[t] - v;
    int node = c * 256 + t;
    if (node < N_NODES) {
        row_ptr[node] = beg + excl;
        inn[node] = rsqrtf((float)(v < 1u ? 1u : v));
    }
    cur[t] = beg + excl;
    __syncthreads();
    for (unsigned i = beg + t; i < end; i += 256) {
        int d = tmp_d[i], sv = tmp_s[i];
        unsigned p = atomicAdd(&cur[(unsigned)d & 255u], 1u);
        csr[p] = sv;
    }
}

// ---- K6: outdeg partial histograms, packed u16 pairs in LDS; 512 blocks ----
__global__ void k_odp(const int* __restrict__ src, unsigned* __restrict__ partial) {
    __shared__ unsigned h[ONW];       // 50 KB
    int slice = blockIdx.x & 1, part = blockIdx.x >> 1;
    int lo = slice * ONPS2;
    for (int i = threadIdx.x; i < ONW; i += 256) h[i] = 0;
    __syncthreads();
    int ebase = part * OCH2;
    for (int i = threadIdx.x; i < OCH2; i += 256) {
        int sv = src[ebase + i] - lo;
        if ((unsigned)sv < (unsigned)ONPS2)
            atomicAdd(&h[sv >> 1], 1u << ((sv & 1) * 16));
    }
    __syncthreads();
    unsigned* outp = partial + ((size_t)slice * OPARTS2 + part) * ONW;
    for (int i = threadIdx.x; i < ONW; i += 256) outp[i] = h[i];
}

// ---- K7: reduce packed partials -> on ----
__global__ void k_on(const unsigned* __restrict__ partial, float* __restrict__ on) {
    int t = blockIdx.x * 256 + threadIdx.x;
    if (t >= OSL2 * ONW) return;
    int slice = t / ONW, word = t % ONW;
    const unsigned* p = partial + (size_t)slice * OPARTS2 * ONW + word;
    unsigned slo = 0, shi = 0;
    for (int q = 0; q < OPARTS2; ++q) {
        unsigned v = p[(size_t)q * ONW];
        slo += v & 0xffffu; shi += v >> 16;
    }
    float2 o;
    o.x = rsqrtf((float)(slo < 1u ? 1u : slo));
    o.y = rsqrtf((float)(shi < 1u ? 1u : shi));
    ((float2*)on)[(slice * ONPS2) / 2 + word] = o;
}

// ---------------- GEMM helpers ----------------
#define FMA4(A, S, WV) { (A).x += (S)*(WV).x; (A).y += (S)*(WV).y; (A).z += (S)*(WV).z; (A).w += (S)*(WV).w; }

__device__ __forceinline__ unsigned bf16rn(float f) {
    unsigned u = __float_as_uint(f);
    return (u + 0x7fffu + ((u >> 16) & 1u)) >> 16;   // RNE bf16 bits
}
__device__ __forceinline__ float lo16f(unsigned v) { return __uint_as_float(v << 16); }
__device__ __forceinline__ float hi16f(unsigned v) { return __uint_as_float(v & 0xffff0000u); }

// GEMM1: h_bf16 = bf16((x * on[:,None]) @ W1)  (50000x128 @ 128x128), j-half per block
__global__ __launch_bounds__(256, 4) void gcn_gemm1_kernel(
        const float* __restrict__ x, const float* __restrict__ on,
        const float* __restrict__ W, unsigned* __restrict__ hb) {
    __shared__ float4 Ws[128 * 16];      // 32 KiB: half of W's columns
    int tid = threadIdx.x;
    int tile = blockIdx.x >> 1, half = blockIdx.x & 1;
    for (int i = tid; i < 128 * 16; i += 256) {
        int k = i >> 4, q = i & 15;
        Ws[i] = ((const float4*)W)[k * 32 + half * 16 + q];
    }
    __syncthreads();

    int jg = tid & 15;
    int ns = tid >> 4;
    int n0 = tile * 64 + ns * 4;

    float sc[4]; bool val[4];
    float4 acc[4];
    #pragma unroll
    for (int i = 0; i < 4; ++i) {
        int n = n0 + i; val[i] = (n < N_NODES);
        sc[i] = val[i] ? on[n] : 0.f;
        acc[i] = float4{0.f, 0.f, 0.f, 0.f};
    }

    const float4* xv4 = (const float4*)x;
    float4 xc[4], wc[4], xn[4], wn[4];
    #pragma unroll
    for (int i = 0; i < 4; ++i)
        xc[i] = val[i] ? xv4[(size_t)(n0 + i) * 32] : float4{0.f, 0.f, 0.f, 0.f};
    #pragma unroll
    for (int t = 0; t < 4; ++t) wc[t] = Ws[t * 16 + jg];

    for (int kc = 0; kc < 32; ++kc) {
        if (kc < 31) {
            #pragma unroll
            for (int i = 0; i < 4; ++i)
                xn[i] = val[i] ? xv4[(size_t)(n0 + i) * 32 + kc + 1] : float4{0.f, 0.f, 0.f, 0.f};
            #pragma unroll
            for (int t = 0; t < 4; ++t) wn[t] = Ws[(kc * 4 + 4 + t) * 16 + jg];
        }
        #pragma unroll
        for (int i = 0; i < 4; ++i) {
            FMA4(acc[i], xc[i].x, wc[0]);
            FMA4(acc[i], xc[i].y, wc[1]);
            FMA4(acc[i], xc[i].z, wc[2]);
            FMA4(acc[i], xc[i].w, wc[3]);
        }
        #pragma unroll
        for (int i = 0; i < 4; ++i) xc[i] = xn[i];
        #pragma unroll
        for (int t = 0; t < 4; ++t) wc[t] = wn[t];
    }
    #pragma unroll
    for (int i = 0; i < 4; ++i) {
        if (val[i]) {
            float ax = acc[i].x * sc[i], ay = acc[i].y * sc[i];
            float az = acc[i].z * sc[i], aw = acc[i].w * sc[i];
            uint2 p;
            p.x = bf16rn(ax) | (bf16rn(ay) << 16);
            p.y = bf16rn(az) | (bf16rn(aw) << 16);
            ((uint2*)hb)[(size_t)(n0 + i) * 32 + half * 16 + jg] = p;
        }
    }
}

// GEMM2: h2_bf16 = bf16((h1 * on[:,None]) @ W2)  (50000x128 @ 128x64)
__global__ __launch_bounds__(256, 4) void gcn_gemm2_kernel(
        const float* __restrict__ h1, const float* __restrict__ on,
        const float* __restrict__ W, unsigned* __restrict__ h2b) {
    __shared__ float4 Ws[128 * 16];      // 32 KiB: all of W2
    int tid = threadIdx.x;
    int tile = blockIdx.x;
    for (int i = tid; i < 128 * 16; i += 256) Ws[i] = ((const float4*)W)[i];
    __syncthreads();

    int jg = tid & 15;
    int ns = tid >> 4;
    int n0 = tile * 64 + ns * 4;

    float sc[4]; bool val[4];
    float4 acc[4];
    #pragma unroll
    for (int i = 0; i < 4; ++i) {
        int n = n0 + i; val[i] = (n < N_NODES);
        sc[i] = val[i] ? on[n] : 0.f;
        acc[i] = float4{0.f, 0.f, 0.f, 0.f};
    }

    const float4* xv4 = (const float4*)h1;
    float4 xc[4], wc[4], xn[4], wn[4];
    #pragma unroll
    for (int i = 0; i < 4; ++i)
        xc[i] = val[i] ? xv4[(size_t)(n0 + i) * 32] : float4{0.f, 0.f, 0.f, 0.f};
    #pragma unroll
    for (int t = 0; t < 4; ++t) wc[t] = Ws[t * 16 + jg];

    for (int kc = 0; kc < 32; ++kc) {
        if (kc < 31) {
            #pragma unroll
            for (int i = 0; i < 4; ++i)
                xn[i] = val[i] ? xv4[(size_t)(n0 + i) * 32 + kc + 1] : float4{0.f, 0.f, 0.f, 0.f};
            #pragma unroll
            for (int t = 0; t < 4; ++t) wn[t] = Ws[(kc * 4 + 4 + t) * 16 + jg];
        }
        #pragma unroll
        for (int i = 0; i < 4; ++i) {
            FMA4(acc[i], xc[i].x, wc[0]);
            FMA4(acc[i], xc[i].y, wc[1]);
            FMA4(acc[i], xc[i].z, wc[2]);
            FMA4(acc[i], xc[i].w, wc[3]);
        }
        #pragma unroll
        for (int i = 0; i < 4; ++i) xc[i] = xn[i];
        #pragma unroll
        for (int t = 0; t < 4; ++t) wc[t] = wn[t];
    }
    #pragma unroll
    for (int i = 0; i < 4; ++i) {
        if (val[i]) {
            float ax = acc[i].x * sc[i], ay = acc[i].y * sc[i];
            float az = acc[i].z * sc[i], aw = acc[i].w * sc[i];
            uint2 p;
            p.x = bf16rn(ax) | (bf16rn(ay) << 16);
            p.y = bf16rn(az) | (bf16rn(aw) << 16);
            ((uint2*)h2b)[(size_t)(n0 + i) * 16 + jg] = p;   // 64 feats = 16 uint2
        }
    }
}

// ---- agg1: h1 = relu(segsum(h_bf16[src]) * inn + b1); wave-per-node, 8-deep MLP ----
__global__ __launch_bounds__(256) void gcn_agg1_kernel(
        const unsigned* __restrict__ hb, const int* __restrict__ csr,
        const unsigned int* __restrict__ row_ptr,
        const float* __restrict__ inn, const float* __restrict__ b1,
        float* __restrict__ h1) {
    int lane = threadIdx.x & 63;
    int n = blockIdx.x * 4 + (threadIdx.x >> 6);   // wave-per-node; 12500 blocks exactly
    unsigned beg = row_ptr[n], end = row_ptr[n + 1];
    float ax = 0.f, ay = 0.f;
    for (unsigned base = beg; base < end; base += 64) {
        unsigned e = base + lane;
        int r = (e < end) ? csr[e] : 0;
        int m = (int)(end - base); if (m > 64) m = 64;
        int j = 0;
        for (; j + 8 <= m; j += 8) {
            unsigned v[8];
            #pragma unroll
            for (int k = 0; k < 8; ++k)
                v[k] = hb[(unsigned)__builtin_amdgcn_readlane(r, j + k) * 64u + (unsigned)lane];
            #pragma unroll
            for (int k = 0; k < 8; ++k) { ax += lo16f(v[k]); ay += hi16f(v[k]); }
        }
        for (; j < m; ++j) {
            unsigned v = hb[(unsigned)__builtin_amdgcn_readlane(r, j) * 64u + (unsigned)lane];
            ax += lo16f(v); ay += hi16f(v);
        }
    }
    float sc = inn[n];
    float2 b = ((const float2*)b1)[lane];
    float2 o;
    o.x = fmaxf(ax * sc + b.x, 0.f);
    o.y = fmaxf(ay * sc + b.y, 0.f);
    ((float2*)h1)[(size_t)n * 64 + lane] = o;
}

// ---- agg2: out = segsum(h2_bf16[src]) * inn + b2; wave-per-node, half-wave edge split ----
__global__ __launch_bounds__(256) void gcn_agg2_kernel(
        const unsigned* __restrict__ h2b, const int* __restrict__ csr,
        const unsigned int* __restrict__ row_ptr,
        const float* __restrict__ inn, const float* __restrict__ b2,
        float* __restrict__ out) {
    int lane = threadIdx.x & 63;
    int n = blockIdx.x * 4 + (threadIdx.x >> 6);
    unsigned beg = row_ptr[n], end = row_ptr[n + 1];
    int half = lane >> 5;        // 0: even edges, 1: odd edges
    unsigned w = (unsigned)(lane & 31);  // word within 32-word row
    float ax = 0.f, ay = 0.f;
    for (unsigned base = beg; base < end; base += 64) {
        unsigned e = base + lane;
        int r = (e < end) ? csr[e] : 0;
        int m = (int)(end - base); if (m > 64) m = 64;
        int j = 0;
        for (; j + 16 <= m; j += 16) {   // 8 loads in flight, 2 edges per load step
            unsigned v[8];
            #pragma unroll
            for (int k = 0; k < 8; ++k)
                v[k] = h2b[(unsigned)__shfl(r, j + 2 * k + half) * 32u + w];
            #pragma unroll
            for (int k = 0; k < 8; ++k) { ax += lo16f(v[k]); ay += hi16f(v[k]); }
        }
        for (; j < m; j += 2) {
            int jj = j + half;
            unsigned v = h2b[(unsigned)__shfl(r, jj < m ? jj : 0) * 32u + w];
            if (jj < m) { ax += lo16f(v); ay += hi16f(v); }
        }
    }
    ax += __shfl_xor(ax, 32);
    ay += __shfl_xor(ay, 32);
    if (half == 0) {
        float sc = inn[n];
        float2 b = ((const float2*)b2)[w];
        float2 o;
        o.x = ax * sc + b.x;
        o.y = ay * sc + b.y;
        ((float2*)out)[(size_t)n * 32 + w] = o;
    }
}

extern "C" void kernel_launch(void* const* d_in, const int* in_sizes, int n_in,
                              void* d_out, int out_size, void* d_ws, size_t ws_size,
                              hipStream_t stream) {
    const float* x  = (const float*)d_in[0];
    const float* W1 = (const float*)d_in[1];
    const float* b1 = (const float*)d_in[2];
    const float* W2 = (const float*)d_in[3];
    const float* b2 = (const float*)d_in[4];
    const int*   src = (const int*)d_in[5];
    const int*   dst = (const int*)d_in[6];
    float* out = (float*)d_out;

    char* ws = (char*)d_ws;
    size_t off = 0;
    auto alloc = [&](size_t bytes) -> void* {
        void* p = ws + off;
        off += (bytes + 255) & ~(size_t)255;
        return p;
    };

    float*        on      = (float*)alloc((size_t)N_NODES * 4);
    float*        inn     = (float*)alloc((size_t)N_NODES * 4);
    unsigned int* row_ptr = (unsigned int*)alloc((size_t)(N_NODES + 1) * 4);
    unsigned int* base    = (unsigned int*)alloc((NCOARSE + 1) * 4);
    unsigned int* tot     = (unsigned int*)alloc(NCOARSE * 4);
    int*          csr     = (int*)alloc((size_t)N_EDGES * 4);
    float*        h       = (float*)alloc((size_t)N_NODES * 128 * 4);   // region A
    float*        h1      = (float*)alloc((size_t)N_NODES * 128 * 4);   // region B

    // region A aliases (temporally disjoint): tmp_d/tmp_s -> hb -> h2b
    int*            tmp_d   = (int*)h;                                   // 6.4 MB
    int*            tmp_s   = (int*)((char*)h + (size_t)N_EDGES * 4);    // 6.4 MB
    unsigned*       hb      = (unsigned*)h;  // 12.8 MB bf16 layer-1 table
    unsigned*       h2b     = (unsigned*)h;  // 6.4 MB bf16 layer-2 table (hb dead after agg1)
    // region B aliases (temporally disjoint): counts/woff -> partial -> h1
    unsigned int*   counts  = (unsigned int*)((char*)h1 + (4u << 20));   // 200 KB
    unsigned int*   woff    = (unsigned int*)((char*)h1 + (8u << 20));   // 200 KB
    unsigned int*   partial = (unsigned int*)h1;                         // 25.6 MB packed u16 pairs

    // ---- CSR build via 2-level counting sort (zero global atomics) ----
    k_hist <<<CBLK, 256, 0, stream>>>(dst, counts);
    k_scanA<<<NCOARSE, 256, 0, stream>>>(counts, woff, tot);
    k_scanB<<<1, 256, 0, stream>>>(tot, base, row_ptr);
    k_scat1<<<CBLK, 256, 0, stream>>>(src, dst, base, woff, tmp_s, tmp_d);
    k_scat2<<<NCOARSE, 256, 0, stream>>>(tmp_s, tmp_d, base, row_ptr, inn, csr);

    // ---- outdeg -> on (packed u16 LDS histograms, 512 blocks; counts/woff dead) ----
    k_odp<<<OSL2 * OPARTS2, 256, 0, stream>>>(src, partial);
    k_on <<<(OSL2 * ONW + 255) / 256, 256, 0, stream>>>(partial, on);

    // ---- GCN layers ----
    int ntiles = (N_NODES + 63) / 64;         // 782
    gcn_gemm1_kernel<<<ntiles * 2, 256, 0, stream>>>(x, on, W1, hb);
    gcn_agg1_kernel<<<N_NODES / 4, 256, 0, stream>>>(hb, csr, row_ptr, inn, b1, h1);
    gcn_gemm2_kernel<<<ntiles, 256, 0, stream>>>(h1, on, W2, h2b);
    gcn_agg2_kernel<<<N_NODES / 4, 256, 0, stream>>>(h2b, csr, row_ptr, inn, b2, out);
}

// Round 9
// 197.337 us; speedup vs baseline: 1.8761x; 1.1716x over previous
//
#include <hip/hip_runtime.h>
#include <cstdint>

#define N_NODES 50000
#define N_EDGES 1600000

#define NCOARSE 196                   // ceil(50000/256)
#define CBLK 256                      // blocks in coarse pass
#define ECHUNK (N_EDGES / CBLK)       // 6250 edges per block

#define OSL2 2                        // outdeg slices
#define ONPS2 (N_NODES / OSL2)        // 25000 nodes per slice
#define ONW (ONPS2 / 2)               // 12500 packed u32 words per slice
#define OPARTS2 256
#define OCH2 (N_EDGES / OPARTS2)      // 6250 edges per part

typedef __attribute__((ext_vector_type(8))) short bf16x8;
typedef __attribute__((ext_vector_type(4))) float f32x4;

// ---- K1: per-block coarse histogram of dst>>8 (LDS atomics only) ----
__global__ void k_hist(const int* __restrict__ dst, unsigned* __restrict__ counts) {
    __shared__ unsigned hist[NCOARSE];
    for (int i = threadIdx.x; i < NCOARSE; i += 256) hist[i] = 0;
    __syncthreads();
    int base = blockIdx.x * ECHUNK;
    for (int i = threadIdx.x; i < ECHUNK; i += 256)
        atomicAdd(&hist[(unsigned)dst[base + i] >> 8], 1u);
    __syncthreads();
    for (int i = threadIdx.x; i < NCOARSE; i += 256)
        counts[blockIdx.x * NCOARSE + i] = hist[i];
}

// ---- K2: scan block-counts within each coarse bucket ----
__global__ void k_scanA(const unsigned* __restrict__ counts, unsigned* __restrict__ woff,
                        unsigned* __restrict__ tot) {
    __shared__ unsigned s[256];
    int c = blockIdx.x, t = threadIdx.x;
    unsigned v = counts[t * NCOARSE + c];
    s[t] = v; __syncthreads();
    for (int o = 1; o < 256; o <<= 1) {
        unsigned u = (t >= o) ? s[t - o] : 0u;
        __syncthreads(); s[t] += u; __syncthreads();
    }
    woff[t * NCOARSE + c] = s[t] - v;
    if (t == 255) tot[c] = s[255];
}

// ---- K3: scan bucket totals -> base[], plus row_ptr tail ----
__global__ void k_scanB(const unsigned* __restrict__ tot, unsigned* __restrict__ base,
                        unsigned* __restrict__ row_ptr) {
    __shared__ unsigned s[256];
    int t = threadIdx.x;
    unsigned v = (t < NCOARSE) ? tot[t] : 0u;
    s[t] = v; __syncthreads();
    for (int o = 1; o < 256; o <<= 1) {
        unsigned u = (t >= o) ? s[t - o] : 0u;
        __syncthreads(); s[t] += u; __syncthreads();
    }
    if (t < NCOARSE) base[t] = s[t] - v;
    if (t == NCOARSE - 1) base[NCOARSE] = s[t];   // == N_EDGES
    if (t == 0) row_ptr[N_NODES] = N_EDGES;
}

// ---- K4: coarse scatter into tmp arrays (LDS cursors, run-coalesced stores) ----
__global__ void k_scat1(const int* __restrict__ src, const int* __restrict__ dst,
                        const unsigned* __restrict__ base, const unsigned* __restrict__ woff,
                        int* __restrict__ tmp_s, int* __restrict__ tmp_d) {
    __shared__ unsigned cur[NCOARSE];
    int b = blockIdx.x, t = threadIdx.x;
    for (int i = t; i < NCOARSE; i += 256) cur[i] = base[i] + woff[b * NCOARSE + i];
    __syncthreads();
    int ebase = b * ECHUNK;
    for (int i = t; i < ECHUNK; i += 256) {
        int d = dst[ebase + i], sv = src[ebase + i];
        unsigned p = atomicAdd(&cur[(unsigned)d >> 8], 1u);
        tmp_d[p] = d; tmp_s[p] = sv;
    }
}

// ---- K5: fine scatter within each coarse bucket; emits row_ptr, inn, csr ----
__global__ void k_scat2(const int* __restrict__ tmp_s, const int* __restrict__ tmp_d,
                        const unsigned* __restrict__ base,
                        unsigned* __restrict__ row_ptr, float* __restrict__ inn,
                        int* __restrict__ csr) {
    __shared__ unsigned hist[256], cur[256], s[256];
    int c = blockIdx.x, t = threadIdx.x;
    unsigned beg = base[c], end = base[c + 1];
    hist[t] = 0;
    __syncthreads();
    for (unsigned i = beg + t; i < end; i += 256)
        atomicAdd(&hist[(unsigned)tmp_d[i] & 255u], 1u);
    __syncthreads();
    unsigned v = hist[t];
    s[t] = v; __syncthreads();
    for (int o = 1; o < 256; o <<= 1) {
        unsigned u = (t >= o) ? s[t - o] : 0u;
        __syncthreads(); s[t] += u; __syncthreads();
    }
    unsigned excl = s[t] - v;
    int node = c * 256 + t;
    if (node < N_NODES) {
        row_ptr[node] = beg + excl;
        inn[node] = rsqrtf((float)(v < 1u ? 1u : v));
    }
    cur[t] = beg + excl;
    __syncthreads();
    for (unsigned i = beg + t; i < end; i += 256) {
        int d = tmp_d[i], sv = tmp_s[i];
        unsigned p = atomicAdd(&cur[(unsigned)d & 255u], 1u);
        csr[p] = sv;
    }
}

// ---- K6: outdeg partial histograms, packed u16 pairs in LDS; 512 blocks ----
__global__ void k_odp(const int* __restrict__ src, unsigned* __restrict__ partial) {
    __shared__ unsigned h[ONW];       // 50 KB
    int slice = blockIdx.x & 1, part = blockIdx.x >> 1;
    int lo = slice * ONPS2;
    for (int i = threadIdx.x; i < ONW; i += 256) h[i] = 0;
    __syncthreads();
    int ebase = part * OCH2;
    for (int i = threadIdx.x; i < OCH2; i += 256) {
        int sv = src[ebase + i] - lo;
        if ((unsigned)sv < (unsigned)ONPS2)
            atomicAdd(&h[sv >> 1], 1u << ((sv & 1) * 16));
    }
    __syncthreads();
    unsigned* outp = partial + ((size_t)slice * OPARTS2 + part) * ONW;
    for (int i = threadIdx.x; i < ONW; i += 256) outp[i] = h[i];
}

// ---- K7: reduce packed partials -> on ----
__global__ void k_on(const unsigned* __restrict__ partial, float* __restrict__ on) {
    int t = blockIdx.x * 256 + threadIdx.x;
    if (t >= OSL2 * ONW) return;
    int slice = t / ONW, word = t % ONW;
    const unsigned* p = partial + (size_t)slice * OPARTS2 * ONW + word;
    unsigned slo = 0, shi = 0;
    for (int q = 0; q < OPARTS2; ++q) {
        unsigned v = p[(size_t)q * ONW];
        slo += v & 0xffffu; shi += v >> 16;
    }
    float2 o;
    o.x = rsqrtf((float)(slo < 1u ? 1u : slo));
    o.y = rsqrtf((float)(shi < 1u ? 1u : shi));
    ((float2*)on)[(slice * ONPS2) / 2 + word] = o;
}

// ---------------- helpers ----------------
__device__ __forceinline__ unsigned bf16rn(float f) {
    unsigned u = __float_as_uint(f);
    return (u + 0x7fffu + ((u >> 16) & 1u)) >> 16;   // RNE bf16 bits
}
__device__ __forceinline__ float lo16f(unsigned v) { return __uint_as_float(v << 16); }
__device__ __forceinline__ float hi16f(unsigned v) { return __uint_as_float(v & 0xffff0000u); }

// ---- W prep: Wt[n][kp] = packed bf16 (W[2kp][n], W[2kp+1][n]) ----
__global__ void k_wprep(const float* __restrict__ W1, const float* __restrict__ W2,
                        unsigned* __restrict__ Wt1, unsigned* __restrict__ Wt2) {
    int t = blockIdx.x * 256 + threadIdx.x;
    if (t < 128 * 64) {
        int n = t >> 6, kp = t & 63;
        Wt1[t] = bf16rn(W1[(2 * kp) * 128 + n]) | (bf16rn(W1[(2 * kp + 1) * 128 + n]) << 16);
    }
    if (t < 64 * 64) {
        int n = t >> 6, kp = t & 63;
        Wt2[t] = bf16rn(W2[(2 * kp) * 64 + n]) | (bf16rn(W2[(2 * kp + 1) * 64 + n]) << 16);
    }
}

// ---- GEMM1 (MFMA): hb = bf16((x * on[:,None]) @ W1), out u16 [50000][128] ----
__global__ __launch_bounds__(256, 2) void gemm1_mfma(
        const float* __restrict__ x, const float* __restrict__ on,
        const unsigned* __restrict__ Wt1, unsigned short* __restrict__ hb) {
    __shared__ uint4 lA4[64 * 16];    // 16 KB: A [m][kp] bf16-packed, XOR-swizzled
    __shared__ uint4 lB4[128 * 16];   // 32 KB: B [n][kp]
    unsigned* lA = (unsigned*)lA4;
    unsigned* lB = (unsigned*)lB4;
    int tid = threadIdx.x;
    int m0 = blockIdx.x * 64;

    for (int i = tid; i < 128 * 64; i += 256) {
        int n = i >> 6, kp = i & 63;
        lB[(n * 64 + kp) ^ ((n & 7) << 2)] = Wt1[i];
    }
    const float2* x2 = (const float2*)x;
    for (int i = tid; i < 64 * 64; i += 256) {
        int m = i >> 6, kp = i & 63;
        int gm = m0 + m;
        float2 v = {0.f, 0.f}; float sc = 0.f;
        if (gm < N_NODES) { v = x2[(size_t)gm * 64 + kp]; sc = on[gm]; }
        lA[(m * 64 + kp) ^ ((m & 7) << 2)] = bf16rn(v.x * sc) | (bf16rn(v.y * sc) << 16);
    }
    __syncthreads();

    int lane = tid & 63, wv = tid >> 6;
    int lm = lane & 15, lg = lane >> 4;
    int ncol0 = wv * 32;

    f32x4 acc[4][2];
    #pragma unroll
    for (int a = 0; a < 4; ++a)
        #pragma unroll
        for (int b = 0; b < 2; ++b) acc[a][b] = f32x4{0.f, 0.f, 0.f, 0.f};

    #pragma unroll
    for (int ks = 0; ks < 4; ++ks) {
        bf16x8 af[4], bfr[2];
        #pragma unroll
        for (int mt = 0; mt < 4; ++mt) {
            int row = mt * 16 + lm;
            af[mt] = __builtin_bit_cast(bf16x8, lA4[(row * 16 + ks * 4 + lg) ^ (row & 7)]);
        }
        #pragma unroll
        for (int nt = 0; nt < 2; ++nt) {
            int row = ncol0 + nt * 16 + lm;
            bfr[nt] = __builtin_bit_cast(bf16x8, lB4[(row * 16 + ks * 4 + lg) ^ (row & 7)]);
        }
        #pragma unroll
        for (int mt = 0; mt < 4; ++mt)
            #pragma unroll
            for (int nt = 0; nt < 2; ++nt)
                acc[mt][nt] = __builtin_amdgcn_mfma_f32_16x16x32_bf16(af[mt], bfr[nt], acc[mt][nt], 0, 0, 0);
    }
    #pragma unroll
    for (int mt = 0; mt < 4; ++mt)
        #pragma unroll
        for (int r = 0; r < 4; ++r) {
            int row = m0 + mt * 16 + lg * 4 + r;      // D: col=lane&15, row=(lane>>4)*4+reg
            if (row < N_NODES) {
                #pragma unroll
                for (int nt = 0; nt < 2; ++nt) {
                    int col = ncol0 + nt * 16 + lm;
                    hb[(size_t)row * 128 + col] = (unsigned short)bf16rn(acc[mt][nt][r]);
                }
            }
        }
}

// ---- GEMM2 (MFMA): h2b = bf16(h1b @ W2), h1b already on-scaled; out u16 [50000][64] ----
__global__ __launch_bounds__(256, 2) void gemm2_mfma(
        const unsigned* __restrict__ h1b, const unsigned* __restrict__ Wt2,
        unsigned short* __restrict__ h2b) {
    __shared__ uint4 lA4[64 * 16];    // 16 KB
    __shared__ uint4 lB4[64 * 16];    // 16 KB
    unsigned* lA = (unsigned*)lA4;
    unsigned* lB = (unsigned*)lB4;
    int tid = threadIdx.x;
    int m0 = blockIdx.x * 64;

    for (int i = tid; i < 64 * 64; i += 256) {
        int n = i >> 6, kp = i & 63;
        lB[(n * 64 + kp) ^ ((n & 7) << 2)] = Wt2[i];
    }
    for (int i = tid; i < 64 * 64; i += 256) {
        int m = i >> 6, kp = i & 63;
        int gm = m0 + m;
        lA[(m * 64 + kp) ^ ((m & 7) << 2)] = (gm < N_NODES) ? h1b[(size_t)gm * 64 + kp] : 0u;
    }
    __syncthreads();

    int lane = tid & 63, wv = tid >> 6;
    int lm = lane & 15, lg = lane >> 4;
    int ncol0 = wv * 16;

    f32x4 acc[4];
    #pragma unroll
    for (int a = 0; a < 4; ++a) acc[a] = f32x4{0.f, 0.f, 0.f, 0.f};

    #pragma unroll
    for (int ks = 0; ks < 4; ++ks) {
        int brow = ncol0 + lm;
        bf16x8 bfr = __builtin_bit_cast(bf16x8, lB4[(brow * 16 + ks * 4 + lg) ^ (brow & 7)]);
        #pragma unroll
        for (int mt = 0; mt < 4; ++mt) {
            int row = mt * 16 + lm;
            bf16x8 af = __builtin_bit_cast(bf16x8, lA4[(row * 16 + ks * 4 + lg) ^ (row & 7)]);
            acc[mt] = __builtin_amdgcn_mfma_f32_16x16x32_bf16(af, bfr, acc[mt], 0, 0, 0);
        }
    }
    #pragma unroll
    for (int mt = 0; mt < 4; ++mt)
        #pragma unroll
        for (int r = 0; r < 4; ++r) {
            int row = m0 + mt * 16 + lg * 4 + r;
            if (row < N_NODES)
                h2b[(size_t)row * 64 + ncol0 + lm] = (unsigned short)bf16rn(acc[mt][r]);
        }
}

// ---- agg1: h1b = bf16(relu(segsum(hb[src])*inn + b1) * on); half-wave pairs, 8-deep ----
__global__ __launch_bounds__(256) void gcn_agg1_kernel(
        const uint2* __restrict__ hb2, const int* __restrict__ csr,
        const unsigned int* __restrict__ row_ptr,
        const float* __restrict__ inn, const float* __restrict__ b1,
        const float* __restrict__ on, unsigned* __restrict__ h1b) {
    int lane = threadIdx.x & 63;
    int n = blockIdx.x * 4 + (threadIdx.x >> 6);
    unsigned beg = row_ptr[n], end = row_ptr[n + 1];
    int half = lane >> 5;
    unsigned w = (unsigned)(lane & 31);
    float a0 = 0.f, a1 = 0.f, a2 = 0.f, a3 = 0.f;
    for (unsigned base = beg; base < end; base += 64) {
        unsigned e = base + lane;
        int r = (e < end) ? csr[e] : 0;
        int m = (int)(end - base); if (m > 64) m = 64;
        for (int j = 0; j < m; j += 16) {
            uint2 v[8]; bool g[8];
            #pragma unroll
            for (int k = 0; k < 8; ++k) {
                int jj = j + 2 * k + half;
                g[k] = jj < m;
                unsigned idx = (unsigned)__shfl(r, g[k] ? jj : 0);
                v[k] = hb2[(size_t)idx * 32 + w];
            }
            #pragma unroll
            for (int k = 0; k < 8; ++k) if (g[k]) {
                a0 += lo16f(v[k].x); a1 += hi16f(v[k].x);
                a2 += lo16f(v[k].y); a3 += hi16f(v[k].y);
            }
        }
    }
    a0 += __shfl_xor(a0, 32); a1 += __shfl_xor(a1, 32);
    a2 += __shfl_xor(a2, 32); a3 += __shfl_xor(a3, 32);
    if (half == 0) {
        float sc = inn[n], osc = on[n];
        float4 b = ((const float4*)b1)[w];
        float f0 = fmaxf(a0 * sc + b.x, 0.f) * osc;
        float f1 = fmaxf(a1 * sc + b.y, 0.f) * osc;
        float f2 = fmaxf(a2 * sc + b.z, 0.f) * osc;
        float f3 = fmaxf(a3 * sc + b.w, 0.f) * osc;
        uint2 o;
        o.x = bf16rn(f0) | (bf16rn(f1) << 16);
        o.y = bf16rn(f2) | (bf16rn(f3) << 16);
        ((uint2*)h1b)[(size_t)n * 32 + w] = o;
    }
}

// ---- agg2: out = segsum(h2b[src])*inn + b2; quarter-wave, 8-deep (32 edges in flight) ----
__global__ __launch_bounds__(256) void gcn_agg2_kernel(
        const uint2* __restrict__ h2b2, const int* __restrict__ csr,
        const unsigned int* __restrict__ row_ptr,
        const float* __restrict__ inn, const float* __restrict__ b2,
        float* __restrict__ out) {
    int lane = threadIdx.x & 63;
    int n = blockIdx.x * 4 + (threadIdx.x >> 6);
    unsigned beg = row_ptr[n], end = row_ptr[n + 1];
    int q = lane >> 4;
    unsigned w = (unsigned)(lane & 15);
    float a0 = 0.f, a1 = 0.f, a2 = 0.f, a3 = 0.f;
    for (unsigned base = beg; base < end; base += 64) {
        unsigned e = base + lane;
        int r = (e < end) ? csr[e] : 0;
        int m = (int)(end - base); if (m > 64) m = 64;
        for (int j = 0; j < m; j += 32) {
            uint2 v[8]; bool g[8];
            #pragma unroll
            for (int k = 0; k < 8; ++k) {
                int jj = j + 4 * k + q;
                g[k] = jj < m;
                unsigned idx = (unsigned)__shfl(r, g[k] ? jj : 0);
                v[k] = h2b2[(size_t)idx * 16 + w];
            }
            #pragma unroll
            for (int k = 0; k < 8; ++k) if (g[k]) {
                a0 += lo16f(v[k].x); a1 += hi16f(v[k].x);
                a2 += lo16f(v[k].y); a3 += hi16f(v[k].y);
            }
        }
    }
    a0 += __shfl_xor(a0, 16); a1 += __shfl_xor(a1, 16);
    a2 += __shfl_xor(a2, 16); a3 += __shfl_xor(a3, 16);
    a0 += __shfl_xor(a0, 32); a1 += __shfl_xor(a1, 32);
    a2 += __shfl_xor(a2, 32); a3 += __shfl_xor(a3, 32);
    if (lane < 16) {
        float sc = inn[n];
        float4 b = ((const float4*)b2)[w];
        float4 o;
        o.x = a0 * sc + b.x; o.y = a1 * sc + b.y;
        o.z = a2 * sc + b.z; o.w = a3 * sc + b.w;
        ((float4*)out)[(size_t)n * 16 + w] = o;
    }
}

extern "C" void kernel_launch(void* const* d_in, const int* in_sizes, int n_in,
                              void* d_out, int out_size, void* d_ws, size_t ws_size,
                              hipStream_t stream) {
    const float* x  = (const float*)d_in[0];
    const float* W1 = (const float*)d_in[1];
    const float* b1 = (const float*)d_in[2];
    const float* W2 = (const float*)d_in[3];
    const float* b2 = (const float*)d_in[4];
    const int*   src = (const int*)d_in[5];
    const int*   dst = (const int*)d_in[6];
    float* out = (float*)d_out;

    char* ws = (char*)d_ws;
    size_t off = 0;
    auto alloc = [&](size_t bytes) -> void* {
        void* p = ws + off;
        off += (bytes + 255) & ~(size_t)255;
        return p;
    };

    float*        on      = (float*)alloc((size_t)N_NODES * 4);
    float*        inn     = (float*)alloc((size_t)N_NODES * 4);
    unsigned int* row_ptr = (unsigned int*)alloc((size_t)(N_NODES + 1) * 4);
    unsigned int* base    = (unsigned int*)alloc((NCOARSE + 1) * 4);
    unsigned int* tot     = (unsigned int*)alloc(NCOARSE * 4);
    unsigned int* Wt1     = (unsigned int*)alloc(128 * 64 * 4);
    unsigned int* Wt2     = (unsigned int*)alloc(64 * 64 * 4);
    int*          csr     = (int*)alloc((size_t)N_EDGES * 4);
    float*        h       = (float*)alloc((size_t)N_NODES * 128 * 4);   // region A
    float*        h1      = (float*)alloc((size_t)N_NODES * 128 * 4);   // region B

    // region A aliases (temporally disjoint): tmp_d/tmp_s -> hb -> h2b
    int*            tmp_d   = (int*)h;                                   // 6.4 MB
    int*            tmp_s   = (int*)((char*)h + (size_t)N_EDGES * 4);    // 6.4 MB
    unsigned short* hb      = (unsigned short*)h;   // 12.8 MB bf16 layer-1 table
    unsigned short* h2b     = (unsigned short*)h;   // 6.4 MB bf16 layer-2 table (hb dead after agg1)
    // region B aliases (temporally disjoint): counts/woff -> partial -> h1b
    unsigned int*   counts  = (unsigned int*)((char*)h1 + (4u << 20));   // 200 KB
    unsigned int*   woff    = (unsigned int*)((char*)h1 + (8u << 20));   // 200 KB
    unsigned int*   partial = (unsigned int*)h1;                         // 25.6 MB packed u16 pairs
    unsigned int*   h1b     = (unsigned int*)h1;                         // 12.8 MB bf16 h1*on table

    // ---- CSR build via 2-level counting sort (zero global atomics) ----
    k_wprep<<<32, 256, 0, stream>>>(W1, W2, Wt1, Wt2);
    k_hist <<<CBLK, 256, 0, stream>>>(dst, counts);
    k_scanA<<<NCOARSE, 256, 0, stream>>>(counts, woff, tot);
    k_scanB<<<1, 256, 0, stream>>>(tot, base, row_ptr);
    k_scat1<<<CBLK, 256, 0, stream>>>(src, dst, base, woff, tmp_s, tmp_d);
    k_scat2<<<NCOARSE, 256, 0, stream>>>(tmp_s, tmp_d, base, row_ptr, inn, csr);

    // ---- outdeg -> on (packed u16 LDS histograms; counts/woff dead after scans) ----
    k_odp<<<OSL2 * OPARTS2, 256, 0, stream>>>(src, partial);
    k_on <<<(OSL2 * ONW + 255) / 256, 256, 0, stream>>>(partial, on);

    // ---- GCN layers (MFMA GEMMs + gather aggregations) ----
    int ntiles = (N_NODES + 63) / 64;         // 782
    gemm1_mfma<<<ntiles, 256, 0, stream>>>(x, on, Wt1, hb);
    gcn_agg1_kernel<<<N_NODES / 4, 256, 0, stream>>>((const uint2*)hb, csr, row_ptr, inn, b1, on, h1b);
    gemm2_mfma<<<ntiles, 256, 0, stream>>>(h1b, Wt2, h2b);
    gcn_agg2_kernel<<<N_NODES / 4, 256, 0, stream>>>((const uint2*)h2b, csr, row_ptr, inn, b2, out);
}